// Round 11
// baseline (795.808 us; speedup 1.0000x reference)
//
#include <hip/hip_runtime.h>

// MoE switch layer: B=8, N=2048, D=1024, E=8, DFF=4096, CAP=320
#define Bq 8
#define Nq 2048
#define Dq 1024
#define Eq 8
#define DFFq 4096
#define CAPq 320
#define Mq (Bq * CAPq)   // 2560 rows per expert
#define Tq (Bq * Nq)     // 16384 tokens

typedef __attribute__((ext_vector_type(8))) short bf16x8;
typedef __attribute__((ext_vector_type(4))) float f32x4;

static __device__ __forceinline__ unsigned short f2bf(float f) {
    union { float f; unsigned u; } v;
    v.f = f;
    unsigned r = v.u + 0x7fffu + ((v.u >> 16) & 1u);   // RNE
    return (unsigned short)(r >> 16);
}

static __device__ __forceinline__ void gload_lds16(const void* g, void* l) {
    __builtin_amdgcn_global_load_lds(
        (const __attribute__((address_space(1))) unsigned int*)g,
        (__attribute__((address_space(3))) unsigned int*)l, 16, 0, 0);
}

// ---------------- routing: logits -> softmax -> argmax/gate ----------------
__global__ __launch_bounds__(256) void route_kernel(
    const float* __restrict__ tok, const float* __restrict__ Wg,
    int* __restrict__ eidx, float* __restrict__ gate)
{
    int wv = threadIdx.x >> 6, lane = threadIdx.x & 63;
    int t = blockIdx.x * 4 + wv;
    const float* tp = tok + (size_t)t * Dq;
    float acc[8] = {0.f,0.f,0.f,0.f,0.f,0.f,0.f,0.f};
    for (int it = 0; it < Dq / 64; ++it) {
        int d = it * 64 + lane;
        float x = tp[d];
        const float4* w = (const float4*)(Wg + (size_t)d * 8);
        float4 w0 = w[0], w1 = w[1];
        acc[0] += x * w0.x; acc[1] += x * w0.y; acc[2] += x * w0.z; acc[3] += x * w0.w;
        acc[4] += x * w1.x; acc[5] += x * w1.y; acc[6] += x * w1.z; acc[7] += x * w1.w;
    }
#pragma unroll
    for (int e = 0; e < 8; ++e)
#pragma unroll
        for (int off = 32; off; off >>= 1)
            acc[e] += __shfl_xor(acc[e], off, 64);
    if (lane == 0) {
        float m = acc[0]; int bi = 0;
#pragma unroll
        for (int e = 1; e < 8; ++e) if (acc[e] > m) { m = acc[e]; bi = e; }
        float s = 0.f;
#pragma unroll
        for (int e = 0; e < 8; ++e) s += expf(acc[e] - m);
        eidx[t] = bi;
        gate[t] = 1.0f / s;   // max prob
    }
}

// ------------- slot assignment + zero dropped-token output rows ------------
__global__ __launch_bounds__(64) void slot_kernel(
    const int* __restrict__ eidx, int* __restrict__ tfs,
    float* __restrict__ out)
{
    int b = blockIdx.x >> 3, e = blockIdx.x & 7;
    int lane = threadIdx.x;
    const int* ip = eidx + (size_t)b * Nq;
    int base = (e * Bq + b) * CAPq;
    int cnt = 0;
    for (int it = 0; it < Nq / 64; ++it) {
        int n = it * 64 + lane;
        bool my = (ip[n] == e);
        unsigned long long mask = __ballot(my);
        if (my) {
            int pos = cnt + __popcll(mask & ((1ull << lane) - 1ull));
            if (pos < CAPq) {
                tfs[base + pos] = b * Nq + n;
            } else {
                // dropped token: its output row must be zero
                float4 z = {0.f, 0.f, 0.f, 0.f};
                float4* op = (float4*)(out + (size_t)(b * Nq + n) * Dq);
                for (int q = 0; q < Dq / 4; ++q) op[q] = z;
            }
        }
        cnt += __popcll(mask);
    }
}

// ------------- dispatch: gather token rows -> bf16 expert buffers ----------
__global__ __launch_bounds__(128) void dispatch_kernel(
    const float* __restrict__ tok, const int* __restrict__ tfs,
    unsigned short* __restrict__ X)
{
    int r = blockIdx.x;          // 0 .. E*B*CAP-1
    int t = tfs[r];
    int d0 = threadIdx.x * 8;
    unsigned short o[8];
    if (t < 0) {
#pragma unroll
        for (int k = 0; k < 8; ++k) o[k] = 0;
    } else {
        const float4* p = (const float4*)(tok + (size_t)t * Dq + d0);
        float4 a = p[0], b = p[1];
        o[0]=f2bf(a.x); o[1]=f2bf(a.y); o[2]=f2bf(a.z); o[3]=f2bf(a.w);
        o[4]=f2bf(b.x); o[5]=f2bf(b.y); o[6]=f2bf(b.z); o[7]=f2bf(b.w);
    }
    *(uint4*)(X + (size_t)r * Dq + d0) = *(const uint4*)o;
}

// ------- weight transpose+convert: in [E][R][C] f32 -> out [E][C][R] bf16 --
__global__ __launch_bounds__(256) void transpose_cvt(
    const float* __restrict__ in, unsigned short* __restrict__ out,
    int R, int C)
{
    __shared__ float tile[32][33];
    int e = blockIdx.z;
    int c0 = blockIdx.x * 32, r0 = blockIdx.y * 32;
    int tx = threadIdx.x & 31, ty = threadIdx.x >> 5;
    const float* ip = in + (size_t)e * R * C;
#pragma unroll
    for (int rr = 0; rr < 4; ++rr)
        tile[ty + rr * 8][tx] = ip[(size_t)(r0 + ty + rr * 8) * C + c0 + tx];
    __syncthreads();
    unsigned short* op = out + (size_t)e * R * C;
#pragma unroll
    for (int rr = 0; rr < 4; ++rr)
        op[(size_t)(c0 + ty + rr * 8) * R + r0 + tx] = f2bf(tile[tx][ty + rr * 8]);
}

// ====== 128x128 NT GEMM, BK=32 double-buffer @ r1 LDS footprint ===========
// C[M][N] = A[M][K] * Bt[N][K]^T per expert. 256 thr = 4 waves (2M x 2N),
// per-wave 64x64 (r1-verified frag maps + epilogues). LDS: As/Bs = 2x[128][32]
// bf16 = 32 KiB total -> 4 blocks/CU (r1's TLP) AND double-buffered (r10's
// covered pipeline): stage tile kt+2 AFTER the barrier; vmcnt(0) retires
// loads issued one full body earlier. 64-B rows make each fragment read a
// contiguous 1 KB block -> inherently bank-conflict-free, NO swizzle; staging
// is fully linear. K-loop unrolled x2 so buffer parity is compile-time.
// MODE 0: H = relu(C) as bf16.  MODE 1: scatter rows to Out with gate.
template <int MODE>
__global__ __launch_bounds__(256) void gemm_nt(
    const unsigned short* __restrict__ A,   // [E][M][K] bf16
    const unsigned short* __restrict__ Bt,  // [E][N][K] bf16
    unsigned short* __restrict__ Hout,      // [E][M][N] bf16  (MODE 0)
    float* __restrict__ Out,                // [T][D] f32      (MODE 1)
    const int* __restrict__ tfs,            // [E][M]
    const float* __restrict__ gate,         // [T]
    int M, int N, int K)
{
    __shared__ __align__(16) unsigned short As[2][128 * 32];  // 16 KiB
    __shared__ __align__(16) unsigned short Bs[2][128 * 32];  // 16 KiB
    __shared__ int   t_lds[128];
    __shared__ float g_lds[128];

    const int tid = threadIdx.x;

    // XCD-aware bijective swizzle (grid % 8 == 0 for both GEMMs)
    const int NTB = N >> 7;
    const int MT  = M >> 7;
    const int nwg = MT * NTB * Eq;
    int flat = blockIdx.x;
    int wg = (flat & 7) * (nwg >> 3) + (flat >> 3);
    int e   = wg / (MT * NTB);
    int rem = wg - e * (MT * NTB);
    int mb = rem / NTB, nb = rem - mb * NTB;
    const int m0 = mb << 7, n0 = nb << 7;

    const unsigned short* Ae = A  + (size_t)e * M * K + (size_t)m0 * K;
    const unsigned short* Be = Bt + (size_t)e * N * K + (size_t)n0 * K;

    if (MODE == 1) {
        if (tid < 128) {
            int t = tfs[e * M + m0 + tid];
            t_lds[tid] = t;
            g_lds[tid] = (t >= 0) ? gate[t] : 0.f;
        }
        __syncthreads();   // drain t_lds loads -> clean vmcnt ledger
    }

    const int lane = tid & 63;
    const int wv = tid >> 6;
    const int wr = wv >> 1, wc = wv & 1;
    const int lrow = lane & 15;
    const int lk = lane >> 4;                 // k-chunk 0..3 (8 bf16 = 16B)

    // fragment read bases (linear, conflict-free: 16 rows x 64B contiguous)
    const int ard = (wr * 64 + lrow) * 64 + lk * 16;   // + i*16rows*64
    const int brd = (wc * 64 + lrow) * 64 + lk * 16;   // + j*16rows*64

    // staging: [128][32] bf16 = 8 KB = 256 thr x 16B x 2 insts, all linear.
    // thread -> row tid>>2 (+64 for inst 1), 16B-chunk tid&3.
    const size_t Kb = (size_t)K * 2;
    const char* gAb = (const char*)Ae + (size_t)(tid >> 2) * Kb + (tid & 3) * 16;
    const char* gBb = (const char*)Be + (size_t)(tid >> 2) * Kb + (tid & 3) * 16;
    const int ldst = wv << 10;    // wave-uniform dest (lane x 16B added by HW)

    // tile = K-tile index (32 k-elems = 64 bytes)
    #define STG(tile, buf) {                                                   \
        const char* _ga = gAb + (size_t)(tile) * 64;                           \
        const char* _gb = gBb + (size_t)(tile) * 64;                           \
        gload_lds16(_ga,                    (char*)As + (buf)*8192 + ldst);    \
        gload_lds16(_ga + (size_t)64 * Kb,  (char*)As + (buf)*8192 + 4096 + ldst); \
        gload_lds16(_gb,                    (char*)Bs + (buf)*8192 + ldst);    \
        gload_lds16(_gb + (size_t)64 * Kb,  (char*)Bs + (buf)*8192 + 4096 + ldst); }

    f32x4 acc[4][4] = {};
    const int NK = K >> 5;    // 32 (GEMM1) or 128 (GEMM2); always even

    // prologue: tile0 -> buf0, tile1 -> buf1; wait tile0 (counted: 4 left)
    STG(0, 0);
    STG(1, 1);
    asm volatile("s_waitcnt vmcnt(4)");
    __builtin_amdgcn_s_barrier();
    __builtin_amdgcn_sched_barrier(0);

    #define BODY(kt, buf) {                                                    \
        const char* pa = (const char*)As + (buf) * 8192;                       \
        const char* pb = (const char*)Bs + (buf) * 8192;                       \
        bf16x8 af[4], bfr[4];                                                  \
        _Pragma("unroll")                                                      \
        for (int i = 0; i < 4; ++i)                                            \
            af[i] = *(const bf16x8*)(pa + ard + i * 1024);                     \
        _Pragma("unroll")                                                      \
        for (int j = 0; j < 4; ++j)                                            \
            bfr[j] = *(const bf16x8*)(pb + brd + j * 1024);                    \
        __builtin_amdgcn_s_setprio(1);                                         \
        _Pragma("unroll")                                                      \
        for (int i = 0; i < 4; ++i)                                            \
        _Pragma("unroll")                                                      \
        for (int j = 0; j < 4; ++j)                                            \
            acc[i][j] = __builtin_amdgcn_mfma_f32_16x16x32_bf16(               \
                af[i], bfr[j], acc[i][j], 0, 0, 0);                            \
        __builtin_amdgcn_s_setprio(0);                                         \
        if ((kt) + 1 < NK) {                                                   \
            asm volatile("s_waitcnt vmcnt(0)");                                \
            __builtin_amdgcn_s_barrier();                                      \
            __builtin_amdgcn_sched_barrier(0);                                 \
            if ((kt) + 2 < NK) STG((kt) + 2, buf);                             \
        } }

    for (int kt = 0; kt < NK; kt += 2) {
        BODY(kt, 0);
        BODY(kt + 1, 1);
    }

    if (MODE == 0) {
        unsigned short* Hp = Hout + (size_t)e * M * N;
#pragma unroll
        for (int i = 0; i < 4; ++i) {
            int row = m0 + wr * 64 + i * 16 + lk * 4;
#pragma unroll
            for (int j = 0; j < 4; ++j) {
                int col = n0 + wc * 64 + j * 16 + lrow;
#pragma unroll
                for (int r = 0; r < 4; ++r)
                    Hp[(size_t)(row + r) * N + col] = f2bf(fmaxf(acc[i][j][r], 0.f));
            }
        }
    } else {
#pragma unroll
        for (int i = 0; i < 4; ++i) {
            int rowl = wr * 64 + i * 16 + lk * 4;
#pragma unroll
            for (int r = 0; r < 4; ++r) {
                int t = t_lds[rowl + r];
                if (t < 0) continue;
                float g = g_lds[rowl + r];
#pragma unroll
                for (int j = 0; j < 4; ++j) {
                    int col = n0 + wc * 64 + j * 16 + lrow;
                    Out[(size_t)t * Dq + col] = g * acc[i][j][r];
                }
            }
        }
    }
    #undef STG
    #undef BODY
}

// ---------------------------------------------------------------------------
extern "C" void kernel_launch(void* const* d_in, const int* in_sizes, int n_in,
                              void* d_out, int out_size, void* d_ws, size_t ws_size,
                              hipStream_t stream)
{
    const float* tok = (const float*)d_in[0];
    const float* Wg  = (const float*)d_in[1];
    const float* W1  = (const float*)d_in[2];
    const float* W2  = (const float*)d_in[3];
    float* out = (float*)d_out;
    char* ws = (char*)d_ws;

    // workspace layout (bytes)
    unsigned short* W1T = (unsigned short*)(ws);                    // [E][DFF][D] bf16  67108864
    unsigned short* W2T = (unsigned short*)(ws + 67108864);         // [E][D][DFF] bf16  67108864
    unsigned short* X   = (unsigned short*)(ws + 134217728);        // [E][M][D]  bf16   41943040
    unsigned short* H   = (unsigned short*)(ws + 176160768);        // [E][M][DFF] bf16 167772160
    int*   tfs  = (int*)(ws + 343932928);                           // [E][M]            81920
    int*   eidx = (int*)(ws + 344014848);                           // [T]               65536
    float* gate = (float*)(ws + 344080384);                         // [T]               65536

    hipMemsetAsync(tfs, 0xFF, Eq * Mq * 4, stream);

    route_kernel<<<Tq / 4, 256, 0, stream>>>(tok, Wg, eidx, gate);
    slot_kernel<<<Bq * Eq, 64, 0, stream>>>(eidx, tfs, out);
    dispatch_kernel<<<Eq * Mq, 128, 0, stream>>>(tok, tfs, X);
    transpose_cvt<<<dim3(DFFq / 32, Dq / 32, Eq), 256, 0, stream>>>(W1, W1T, Dq, DFFq);
    transpose_cvt<<<dim3(Dq / 32, DFFq / 32, Eq), 256, 0, stream>>>(W2, W2T, DFFq, Dq);

    // GEMM1: H = relu(X @ W1): 20 x 32 x 8 = 5120 blocks @ up to 4/CU
    gemm_nt<0><<<(Mq / 128) * (DFFq / 128) * Eq, 256, 0, stream>>>(
        X, W1T, H, nullptr, nullptr, nullptr, Mq, DFFq, Dq);
    // GEMM2: out[token] = gate * (H @ W2): 20 x 8 x 8 = 1280 blocks
    gemm_nt<1><<<(Mq / 128) * (Dq / 128) * Eq, 256, 0, stream>>>(
        H, W2T, nullptr, out, tfs, gate, Mq, Dq, DFFq);
}

// Round 12
// 564.588 us; speedup vs baseline: 1.4095x; 1.4095x over previous
//
#include <hip/hip_runtime.h>

// MoE switch layer: B=8, N=2048, D=1024, E=8, DFF=4096, CAP=320
#define Bq 8
#define Nq 2048
#define Dq 1024
#define Eq 8
#define DFFq 4096
#define CAPq 320
#define Mq (Bq * CAPq)   // 2560 rows per expert
#define Tq (Bq * Nq)     // 16384 tokens

typedef __attribute__((ext_vector_type(8))) short bf16x8;
typedef __attribute__((ext_vector_type(4))) float f32x4;

static __device__ __forceinline__ unsigned short f2bf(float f) {
    union { float f; unsigned u; } v;
    v.f = f;
    unsigned r = v.u + 0x7fffu + ((v.u >> 16) & 1u);   // RNE
    return (unsigned short)(r >> 16);
}

static __device__ __forceinline__ void gload_lds16(const void* g, void* l) {
    __builtin_amdgcn_global_load_lds(
        (const __attribute__((address_space(1))) unsigned int*)g,
        (__attribute__((address_space(3))) unsigned int*)l, 16, 0, 0);
}

// ---------------- routing: logits -> softmax -> argmax/gate ----------------
__global__ __launch_bounds__(256) void route_kernel(
    const float* __restrict__ tok, const float* __restrict__ Wg,
    int* __restrict__ eidx, float* __restrict__ gate)
{
    int wv = threadIdx.x >> 6, lane = threadIdx.x & 63;
    int t = blockIdx.x * 4 + wv;
    const float* tp = tok + (size_t)t * Dq;
    float acc[8] = {0.f,0.f,0.f,0.f,0.f,0.f,0.f,0.f};
    for (int it = 0; it < Dq / 64; ++it) {
        int d = it * 64 + lane;
        float x = tp[d];
        const float4* w = (const float4*)(Wg + (size_t)d * 8);
        float4 w0 = w[0], w1 = w[1];
        acc[0] += x * w0.x; acc[1] += x * w0.y; acc[2] += x * w0.z; acc[3] += x * w0.w;
        acc[4] += x * w1.x; acc[5] += x * w1.y; acc[6] += x * w1.z; acc[7] += x * w1.w;
    }
#pragma unroll
    for (int e = 0; e < 8; ++e)
#pragma unroll
        for (int off = 32; off; off >>= 1)
            acc[e] += __shfl_xor(acc[e], off, 64);
    if (lane == 0) {
        float m = acc[0]; int bi = 0;
#pragma unroll
        for (int e = 1; e < 8; ++e) if (acc[e] > m) { m = acc[e]; bi = e; }
        float s = 0.f;
#pragma unroll
        for (int e = 0; e < 8; ++e) s += expf(acc[e] - m);
        eidx[t] = bi;
        gate[t] = 1.0f / s;   // max prob
    }
}

// ------------- slot assignment + zero dropped-token output rows ------------
__global__ __launch_bounds__(64) void slot_kernel(
    const int* __restrict__ eidx, int* __restrict__ tfs,
    float* __restrict__ out)
{
    int b = blockIdx.x >> 3, e = blockIdx.x & 7;
    int lane = threadIdx.x;
    const int* ip = eidx + (size_t)b * Nq;
    int base = (e * Bq + b) * CAPq;
    int cnt = 0;
    for (int it = 0; it < Nq / 64; ++it) {
        int n = it * 64 + lane;
        bool my = (ip[n] == e);
        unsigned long long mask = __ballot(my);
        if (my) {
            int pos = cnt + __popcll(mask & ((1ull << lane) - 1ull));
            if (pos < CAPq) {
                tfs[base + pos] = b * Nq + n;
            } else {
                // dropped token: its output row must be zero
                float4 z = {0.f, 0.f, 0.f, 0.f};
                float4* op = (float4*)(out + (size_t)(b * Nq + n) * Dq);
                for (int q = 0; q < Dq / 4; ++q) op[q] = z;
            }
        }
        cnt += __popcll(mask);
    }
}

// ------------- dispatch: gather token rows -> bf16 expert buffers ----------
__global__ __launch_bounds__(128) void dispatch_kernel(
    const float* __restrict__ tok, const int* __restrict__ tfs,
    unsigned short* __restrict__ X)
{
    int r = blockIdx.x;          // 0 .. E*B*CAP-1
    int t = tfs[r];
    int d0 = threadIdx.x * 8;
    unsigned short o[8];
    if (t < 0) {
#pragma unroll
        for (int k = 0; k < 8; ++k) o[k] = 0;
    } else {
        const float4* p = (const float4*)(tok + (size_t)t * Dq + d0);
        float4 a = p[0], b = p[1];
        o[0]=f2bf(a.x); o[1]=f2bf(a.y); o[2]=f2bf(a.z); o[3]=f2bf(a.w);
        o[4]=f2bf(b.x); o[5]=f2bf(b.y); o[6]=f2bf(b.z); o[7]=f2bf(b.w);
    }
    *(uint4*)(X + (size_t)r * Dq + d0) = *(const uint4*)o;
}

// ------- weight transpose+convert: in [E][R][C] f32 -> out [E][C][R] bf16 --
// 64x64 tile, float4 loads, LDS [64][65] (2-way banks max on both phases),
// uint4 (8x bf16) coalesced writes (128B per 8-lane cluster).
__global__ __launch_bounds__(256) void transpose_cvt(
    const float* __restrict__ in, unsigned short* __restrict__ out,
    int R, int C)
{
    __shared__ float tile[64][65];
    int e = blockIdx.z;
    int c0 = blockIdx.x * 64, r0 = blockIdx.y * 64;
    const float* ip = in + (size_t)e * R * C;
    int lr  = threadIdx.x >> 4;
    int lc4 = (threadIdx.x & 15) * 4;
#pragma unroll
    for (int i = 0; i < 4; ++i) {
        float4 v = *(const float4*)(ip + (size_t)(r0 + lr + 16 * i) * C + c0 + lc4);
        tile[lr + 16 * i][lc4 + 0] = v.x;
        tile[lr + 16 * i][lc4 + 1] = v.y;
        tile[lr + 16 * i][lc4 + 2] = v.z;
        tile[lr + 16 * i][lc4 + 3] = v.w;
    }
    __syncthreads();
    unsigned short* op = out + (size_t)e * R * C;   // out is [C][R]
    int oc  = threadIdx.x >> 3;    // 0..31 (column within tile, +32 on pass 2)
    int oct = threadIdx.x & 7;     // r-octet 0..7
#pragma unroll
    for (int i = 0; i < 2; ++i) {
        int c = oc + 32 * i;
        unsigned short o[8];
#pragma unroll
        for (int j = 0; j < 8; ++j)
            o[j] = f2bf(tile[oct * 8 + j][c]);
        *(uint4*)(op + (size_t)(c0 + c) * R + r0 + oct * 8) = *(const uint4*)o;
    }
}

// ====== r1-verified 128x128 NT GEMM + XCD-swizzled flat grid + setprio =====
// C[M][N] = A[M][K] * Bt[N][K]^T per expert. 256 thr = 4 waves (2M x 2N),
// per-wave 64x64, BK=64 single buffer, 2-barrier loop (empirically the best
// structure across 11 rounds: 31.5% MfmaUtil, 0 bank conflicts). XCD swizzle
// verified (r10) to cut FETCH 694->180 MB.
// MODE 0: H = relu(C) as bf16.  MODE 1: scatter rows to Out with gate.
template <int MODE>
__global__ __launch_bounds__(256) void gemm_nt(
    const unsigned short* __restrict__ A,   // [E][M][K] bf16
    const unsigned short* __restrict__ Bt,  // [E][N][K] bf16
    unsigned short* __restrict__ Hout,      // [E][M][N] bf16  (MODE 0)
    float* __restrict__ Out,                // [T][D] f32      (MODE 1)
    const int* __restrict__ tfs,            // [E][M]
    const float* __restrict__ gate,         // [T]
    int M, int N, int K)
{
    __shared__ __align__(16) unsigned short As[128 * 64];
    __shared__ __align__(16) unsigned short Bs[128 * 64];
    __shared__ int   t_lds[128];
    __shared__ float g_lds[128];

    const int tid = threadIdx.x;

    // XCD-aware bijective swizzle (grid % 8 == 0 for both GEMMs)
    const int NTB = N >> 7, MT = M >> 7;
    const int nwg = MT * NTB * Eq;
    int flat = blockIdx.x;
    int wg = (flat & 7) * (nwg >> 3) + (flat >> 3);
    int e   = wg / (MT * NTB);
    int rem = wg - e * (MT * NTB);
    int mb = rem / NTB, nb = rem - mb * NTB;
    const int m0 = mb << 7, n0 = nb << 7;

    const unsigned short* Ae = A  + (size_t)e * M * K + (size_t)m0 * K;
    const unsigned short* Be = Bt + (size_t)e * N * K + (size_t)n0 * K;

    if (MODE == 1 && tid < 128) {
        int t = tfs[e * M + m0 + tid];
        t_lds[tid] = t;
        g_lds[tid] = (t >= 0) ? gate[t] : 0.f;
    }

    const int lane = tid & 63;
    const int wv = tid >> 6;
    const int wr = wv >> 1, wc = wv & 1;
    const int lrow = lane & 15;
    const int lk = lane >> 4;
    const int swz = (lrow & 7) << 4;

    // staging decode (constant per thread): LDS off = inst*4096 + tid*16
    const int srow = tid >> 3;                                     // row within 32-row chunk
    const int skb  = ((tid & 7) << 4) ^ (((tid >> 3) & 7) << 4);   // pre-swizzled src byte
    const int ldst = (tid >> 6) << 10;                             // wave-uniform dest

    f32x4 acc[4][4] = {};

    for (int kt = 0; kt < K; kt += 64) {
        __syncthreads();
        const char* ga = (const char*)Ae + ((size_t)srow * K + kt) * 2 + skb;
        const char* gb = (const char*)Be + ((size_t)srow * K + kt) * 2 + skb;
#pragma unroll
        for (int inst = 0; inst < 4; ++inst) {
            gload_lds16(ga + (size_t)(inst * 32) * K * 2, (char*)As + inst * 4096 + ldst);
            gload_lds16(gb + (size_t)(inst * 32) * K * 2, (char*)Bs + inst * 4096 + ldst);
        }
        __syncthreads();
#pragma unroll
        for (int kk = 0; kk < 2; ++kk) {
            bf16x8 af[4], bfr[4];
#pragma unroll
            for (int i = 0; i < 4; ++i) {
                int row = wr * 64 + i * 16 + lrow;
                int addr = row * 128 + ((kk * 64 + lk * 16) ^ swz);
                af[i] = *(const bf16x8*)((const char*)As + addr);
            }
#pragma unroll
            for (int j = 0; j < 4; ++j) {
                int row = wc * 64 + j * 16 + lrow;
                int addr = row * 128 + ((kk * 64 + lk * 16) ^ swz);
                bfr[j] = *(const bf16x8*)((const char*)Bs + addr);
            }
            __builtin_amdgcn_s_setprio(1);
#pragma unroll
            for (int i = 0; i < 4; ++i)
#pragma unroll
                for (int j = 0; j < 4; ++j)
                    acc[i][j] = __builtin_amdgcn_mfma_f32_16x16x32_bf16(
                        af[i], bfr[j], acc[i][j], 0, 0, 0);
            __builtin_amdgcn_s_setprio(0);
        }
    }

    if (MODE == 0) {
        unsigned short* Hp = Hout + (size_t)e * M * N;
#pragma unroll
        for (int i = 0; i < 4; ++i) {
            int row = m0 + wr * 64 + i * 16 + lk * 4;
#pragma unroll
            for (int j = 0; j < 4; ++j) {
                int col = n0 + wc * 64 + j * 16 + lrow;
#pragma unroll
                for (int r = 0; r < 4; ++r)
                    Hp[(size_t)(row + r) * N + col] = f2bf(fmaxf(acc[i][j][r], 0.f));
            }
        }
    } else {
#pragma unroll
        for (int i = 0; i < 4; ++i) {
            int rowl = wr * 64 + i * 16 + lk * 4;
#pragma unroll
            for (int r = 0; r < 4; ++r) {
                int t = t_lds[rowl + r];
                if (t < 0) continue;
                float g = g_lds[rowl + r];
#pragma unroll
                for (int j = 0; j < 4; ++j) {
                    int col = n0 + wc * 64 + j * 16 + lrow;
                    Out[(size_t)t * Dq + col] = g * acc[i][j][r];
                }
            }
        }
    }
}

// ---------------------------------------------------------------------------
extern "C" void kernel_launch(void* const* d_in, const int* in_sizes, int n_in,
                              void* d_out, int out_size, void* d_ws, size_t ws_size,
                              hipStream_t stream)
{
    const float* tok = (const float*)d_in[0];
    const float* Wg  = (const float*)d_in[1];
    const float* W1  = (const float*)d_in[2];
    const float* W2  = (const float*)d_in[3];
    float* out = (float*)d_out;
    char* ws = (char*)d_ws;

    // workspace layout (bytes)
    unsigned short* W1T = (unsigned short*)(ws);                    // [E][DFF][D] bf16  67108864
    unsigned short* W2T = (unsigned short*)(ws + 67108864);         // [E][D][DFF] bf16  67108864
    unsigned short* X   = (unsigned short*)(ws + 134217728);        // [E][M][D]  bf16   41943040
    unsigned short* H   = (unsigned short*)(ws + 176160768);        // [E][M][DFF] bf16 167772160
    int*   tfs  = (int*)(ws + 343932928);                           // [E][M]            81920
    int*   eidx = (int*)(ws + 344014848);                           // [T]               65536
    float* gate = (float*)(ws + 344080384);                         // [T]               65536

    hipMemsetAsync(tfs, 0xFF, Eq * Mq * 4, stream);

    route_kernel<<<Tq / 4, 256, 0, stream>>>(tok, Wg, eidx, gate);
    slot_kernel<<<Bq * Eq, 64, 0, stream>>>(eidx, tfs, out);
    dispatch_kernel<<<Eq * Mq, 128, 0, stream>>>(tok, tfs, X);

    // W1 transpose immediately before GEMM1 (L2 warmth), W2 before GEMM2
    transpose_cvt<<<dim3(DFFq / 64, Dq / 64, Eq), 256, 0, stream>>>(W1, W1T, Dq, DFFq);
    // GEMM1: H = relu(X @ W1): 20 x 32 x 8 = 5120 blocks
    gemm_nt<0><<<(Mq / 128) * (DFFq / 128) * Eq, 256, 0, stream>>>(
        X, W1T, H, nullptr, nullptr, nullptr, Mq, DFFq, Dq);

    transpose_cvt<<<dim3(Dq / 64, DFFq / 64, Eq), 256, 0, stream>>>(W2, W2T, DFFq, Dq);
    // GEMM2: out[token] = gate * (H @ W2): 20 x 8 x 8 = 1280 blocks
    gemm_nt<1><<<(Mq / 128) * (Dq / 128) * Eq, 256, 0, stream>>>(
        H, W2T, nullptr, out, tfs, gate, Mq, Dq, DFFq);
}

// Round 13
// 540.265 us; speedup vs baseline: 1.4730x; 1.0450x over previous
//
#include <hip/hip_runtime.h>

// MoE switch layer: B=8, N=2048, D=1024, E=8, DFF=4096, CAP=320
#define Bq 8
#define Nq 2048
#define Dq 1024
#define Eq 8
#define DFFq 4096
#define CAPq 320
#define Mq (Bq * CAPq)   // 2560 rows per expert
#define Tq (Bq * Nq)     // 16384 tokens

typedef __attribute__((ext_vector_type(8))) short bf16x8;
typedef __attribute__((ext_vector_type(4))) float f32x4;

static __device__ __forceinline__ unsigned short f2bf(float f) {
    union { float f; unsigned u; } v;
    v.f = f;
    unsigned r = v.u + 0x7fffu + ((v.u >> 16) & 1u);   // RNE
    return (unsigned short)(r >> 16);
}

static __device__ __forceinline__ void gload_lds16(const void* g, void* l) {
    __builtin_amdgcn_global_load_lds(
        (const __attribute__((address_space(1))) unsigned int*)g,
        (__attribute__((address_space(3))) unsigned int*)l, 16, 0, 0);
}

// ---------------- routing: logits -> softmax -> argmax/gate ----------------
__global__ __launch_bounds__(256) void route_kernel(
    const float* __restrict__ tok, const float* __restrict__ Wg,
    int* __restrict__ eidx, float* __restrict__ gate)
{
    int wv = threadIdx.x >> 6, lane = threadIdx.x & 63;
    int t = blockIdx.x * 4 + wv;
    const float* tp = tok + (size_t)t * Dq;
    float acc[8] = {0.f,0.f,0.f,0.f,0.f,0.f,0.f,0.f};
    for (int it = 0; it < Dq / 64; ++it) {
        int d = it * 64 + lane;
        float x = tp[d];
        const float4* w = (const float4*)(Wg + (size_t)d * 8);
        float4 w0 = w[0], w1 = w[1];
        acc[0] += x * w0.x; acc[1] += x * w0.y; acc[2] += x * w0.z; acc[3] += x * w0.w;
        acc[4] += x * w1.x; acc[5] += x * w1.y; acc[6] += x * w1.z; acc[7] += x * w1.w;
    }
#pragma unroll
    for (int e = 0; e < 8; ++e)
#pragma unroll
        for (int off = 32; off; off >>= 1)
            acc[e] += __shfl_xor(acc[e], off, 64);
    if (lane == 0) {
        float m = acc[0]; int bi = 0;
#pragma unroll
        for (int e = 1; e < 8; ++e) if (acc[e] > m) { m = acc[e]; bi = e; }
        float s = 0.f;
#pragma unroll
        for (int e = 0; e < 8; ++e) s += expf(acc[e] - m);
        eidx[t] = bi;
        gate[t] = 1.0f / s;   // max prob
    }
}

// ------------- slot assignment + zero dropped-token output rows ------------
__global__ __launch_bounds__(64) void slot_kernel(
    const int* __restrict__ eidx, int* __restrict__ tfs,
    float* __restrict__ out)
{
    int b = blockIdx.x >> 3, e = blockIdx.x & 7;
    int lane = threadIdx.x;
    const int* ip = eidx + (size_t)b * Nq;
    int base = (e * Bq + b) * CAPq;
    int cnt = 0;
    for (int it = 0; it < Nq / 64; ++it) {
        int n = it * 64 + lane;
        bool my = (ip[n] == e);
        unsigned long long mask = __ballot(my);
        if (my) {
            int pos = cnt + __popcll(mask & ((1ull << lane) - 1ull));
            if (pos < CAPq) {
                tfs[base + pos] = b * Nq + n;
            } else {
                // dropped token: its output row must be zero
                float4 z = {0.f, 0.f, 0.f, 0.f};
                float4* op = (float4*)(out + (size_t)(b * Nq + n) * Dq);
                for (int q = 0; q < Dq / 4; ++q) op[q] = z;
            }
        }
        cnt += __popcll(mask);
    }
}

// ------------- dispatch: gather token rows -> bf16 expert buffers ----------
__global__ __launch_bounds__(128) void dispatch_kernel(
    const float* __restrict__ tok, const int* __restrict__ tfs,
    unsigned short* __restrict__ X)
{
    int r = blockIdx.x;          // 0 .. E*B*CAP-1
    int t = tfs[r];
    int d0 = threadIdx.x * 8;
    unsigned short o[8];
    if (t < 0) {
#pragma unroll
        for (int k = 0; k < 8; ++k) o[k] = 0;
    } else {
        const float4* p = (const float4*)(tok + (size_t)t * Dq + d0);
        float4 a = p[0], b = p[1];
        o[0]=f2bf(a.x); o[1]=f2bf(a.y); o[2]=f2bf(a.z); o[3]=f2bf(a.w);
        o[4]=f2bf(b.x); o[5]=f2bf(b.y); o[6]=f2bf(b.z); o[7]=f2bf(b.w);
    }
    *(uint4*)(X + (size_t)r * Dq + d0) = *(const uint4*)o;
}

// ------- weight transpose+convert: in [E][R][C] f32 -> out [E][C][R] bf16 --
// 64x64 tile, float4 loads, LDS [64][65] (2-way banks max on both phases),
// uint4 (8x bf16) coalesced writes (128B per 8-lane cluster).
__global__ __launch_bounds__(256) void transpose_cvt(
    const float* __restrict__ in, unsigned short* __restrict__ out,
    int R, int C)
{
    __shared__ float tile[64][65];
    int e = blockIdx.z;
    int c0 = blockIdx.x * 64, r0 = blockIdx.y * 64;
    const float* ip = in + (size_t)e * R * C;
    int lr  = threadIdx.x >> 4;
    int lc4 = (threadIdx.x & 15) * 4;
#pragma unroll
    for (int i = 0; i < 4; ++i) {
        float4 v = *(const float4*)(ip + (size_t)(r0 + lr + 16 * i) * C + c0 + lc4);
        tile[lr + 16 * i][lc4 + 0] = v.x;
        tile[lr + 16 * i][lc4 + 1] = v.y;
        tile[lr + 16 * i][lc4 + 2] = v.z;
        tile[lr + 16 * i][lc4 + 3] = v.w;
    }
    __syncthreads();
    unsigned short* op = out + (size_t)e * R * C;   // out is [C][R]
    int oc  = threadIdx.x >> 3;    // 0..31 (column within tile, +32 on pass 2)
    int oct = threadIdx.x & 7;     // r-octet 0..7
#pragma unroll
    for (int i = 0; i < 2; ++i) {
        int c = oc + 32 * i;
        unsigned short o[8];
#pragma unroll
        for (int j = 0; j < 8; ++j)
            o[j] = f2bf(tile[oct * 8 + j][c]);
        *(uint4*)(op + (size_t)(c0 + c) * R + r0 + oct * 8) = *(const uint4*)o;
    }
}

// ====== r1-verified 128x128 NT GEMM, XCD swizzle, 4-blocks/CU bound ========
// C[M][N] = A[M][K] * Bt[N][K]^T per expert. 256 thr = 4 waves (2M x 2N),
// per-wave 64x64, BK=64 single buffer, 2-barrier loop (best structure across
// 12 rounds: 32% MfmaUtil, 0 bank conflicts). __launch_bounds__(256, 4):
// 4 waves/EU -> 4 blocks/CU resident (VGPR cap 128, we use ~72; LDS 33.8KB
// x4 = 135KB < 160KB) -> cross-block TLP absorbs the per-K-tile stage drain.
// MODE 0: H = relu(C) as bf16.  MODE 1: scatter rows to Out with gate.
template <int MODE>
__global__ __launch_bounds__(256, 4) void gemm_nt(
    const unsigned short* __restrict__ A,   // [E][M][K] bf16
    const unsigned short* __restrict__ Bt,  // [E][N][K] bf16
    unsigned short* __restrict__ Hout,      // [E][M][N] bf16  (MODE 0)
    float* __restrict__ Out,                // [T][D] f32      (MODE 1)
    const int* __restrict__ tfs,            // [E][M]
    const float* __restrict__ gate,         // [T]
    int M, int N, int K)
{
    __shared__ __align__(16) unsigned short As[128 * 64];
    __shared__ __align__(16) unsigned short Bs[128 * 64];
    __shared__ int   t_lds[128];
    __shared__ float g_lds[128];

    const int tid = threadIdx.x;

    // XCD-aware bijective swizzle (grid % 8 == 0 for both GEMMs)
    const int NTB = N >> 7, MT = M >> 7;
    const int nwg = MT * NTB * Eq;
    int flat = blockIdx.x;
    int wg = (flat & 7) * (nwg >> 3) + (flat >> 3);
    int e   = wg / (MT * NTB);
    int rem = wg - e * (MT * NTB);
    int mb = rem / NTB, nb = rem - mb * NTB;
    const int m0 = mb << 7, n0 = nb << 7;

    const unsigned short* Ae = A  + (size_t)e * M * K + (size_t)m0 * K;
    const unsigned short* Be = Bt + (size_t)e * N * K + (size_t)n0 * K;

    if (MODE == 1 && tid < 128) {
        int t = tfs[e * M + m0 + tid];
        t_lds[tid] = t;
        g_lds[tid] = (t >= 0) ? gate[t] : 0.f;
    }

    const int lane = tid & 63;
    const int wv = tid >> 6;
    const int wr = wv >> 1, wc = wv & 1;
    const int lrow = lane & 15;
    const int lk = lane >> 4;
    const int swz = (lrow & 7) << 4;

    // staging decode (constant per thread): LDS off = inst*4096 + tid*16
    const int srow = tid >> 3;                                     // row within 32-row chunk
    const int skb  = ((tid & 7) << 4) ^ (((tid >> 3) & 7) << 4);   // pre-swizzled src byte
    const int ldst = (tid >> 6) << 10;                             // wave-uniform dest

    f32x4 acc[4][4] = {};

    for (int kt = 0; kt < K; kt += 64) {
        __syncthreads();
        const char* ga = (const char*)Ae + ((size_t)srow * K + kt) * 2 + skb;
        const char* gb = (const char*)Be + ((size_t)srow * K + kt) * 2 + skb;
#pragma unroll
        for (int inst = 0; inst < 4; ++inst) {
            gload_lds16(ga + (size_t)(inst * 32) * K * 2, (char*)As + inst * 4096 + ldst);
            gload_lds16(gb + (size_t)(inst * 32) * K * 2, (char*)Bs + inst * 4096 + ldst);
        }
        __syncthreads();
#pragma unroll
        for (int kk = 0; kk < 2; ++kk) {
            bf16x8 af[4], bfr[4];
#pragma unroll
            for (int i = 0; i < 4; ++i) {
                int row = wr * 64 + i * 16 + lrow;
                int addr = row * 128 + ((kk * 64 + lk * 16) ^ swz);
                af[i] = *(const bf16x8*)((const char*)As + addr);
            }
#pragma unroll
            for (int j = 0; j < 4; ++j) {
                int row = wc * 64 + j * 16 + lrow;
                int addr = row * 128 + ((kk * 64 + lk * 16) ^ swz);
                bfr[j] = *(const bf16x8*)((const char*)Bs + addr);
            }
            __builtin_amdgcn_s_setprio(1);
#pragma unroll
            for (int i = 0; i < 4; ++i)
#pragma unroll
                for (int j = 0; j < 4; ++j)
                    acc[i][j] = __builtin_amdgcn_mfma_f32_16x16x32_bf16(
                        af[i], bfr[j], acc[i][j], 0, 0, 0);
            __builtin_amdgcn_s_setprio(0);
        }
    }

    if (MODE == 0) {
        unsigned short* Hp = Hout + (size_t)e * M * N;
#pragma unroll
        for (int i = 0; i < 4; ++i) {
            int row = m0 + wr * 64 + i * 16 + lk * 4;
#pragma unroll
            for (int j = 0; j < 4; ++j) {
                int col = n0 + wc * 64 + j * 16 + lrow;
#pragma unroll
                for (int r = 0; r < 4; ++r)
                    Hp[(size_t)(row + r) * N + col] = f2bf(fmaxf(acc[i][j][r], 0.f));
            }
        }
    } else {
#pragma unroll
        for (int i = 0; i < 4; ++i) {
            int rowl = wr * 64 + i * 16 + lk * 4;
#pragma unroll
            for (int r = 0; r < 4; ++r) {
                int t = t_lds[rowl + r];
                if (t < 0) continue;
                float g = g_lds[rowl + r];
#pragma unroll
                for (int j = 0; j < 4; ++j) {
                    int col = n0 + wc * 64 + j * 16 + lrow;
                    Out[(size_t)t * Dq + col] = g * acc[i][j][r];
                }
            }
        }
    }
}

// ---------------------------------------------------------------------------
extern "C" void kernel_launch(void* const* d_in, const int* in_sizes, int n_in,
                              void* d_out, int out_size, void* d_ws, size_t ws_size,
                              hipStream_t stream)
{
    const float* tok = (const float*)d_in[0];
    const float* Wg  = (const float*)d_in[1];
    const float* W1  = (const float*)d_in[2];
    const float* W2  = (const float*)d_in[3];
    float* out = (float*)d_out;
    char* ws = (char*)d_ws;

    // workspace layout (bytes)
    unsigned short* W1T = (unsigned short*)(ws);                    // [E][DFF][D] bf16  67108864
    unsigned short* W2T = (unsigned short*)(ws + 67108864);         // [E][D][DFF] bf16  67108864
    unsigned short* X   = (unsigned short*)(ws + 134217728);        // [E][M][D]  bf16   41943040
    unsigned short* H   = (unsigned short*)(ws + 176160768);        // [E][M][DFF] bf16 167772160
    int*   tfs  = (int*)(ws + 343932928);                           // [E][M]            81920
    int*   eidx = (int*)(ws + 344014848);                           // [T]               65536
    float* gate = (float*)(ws + 344080384);                         // [T]               65536

    hipMemsetAsync(tfs, 0xFF, Eq * Mq * 4, stream);

    route_kernel<<<Tq / 4, 256, 0, stream>>>(tok, Wg, eidx, gate);
    slot_kernel<<<Bq * Eq, 64, 0, stream>>>(eidx, tfs, out);
    dispatch_kernel<<<Eq * Mq, 128, 0, stream>>>(tok, tfs, X);

    // W1 transpose immediately before GEMM1 (L2 warmth), W2 before GEMM2
    transpose_cvt<<<dim3(DFFq / 64, Dq / 64, Eq), 256, 0, stream>>>(W1, W1T, Dq, DFFq);
    // GEMM1: H = relu(X @ W1): 20 x 32 x 8 = 5120 blocks
    gemm_nt<0><<<(Mq / 128) * (DFFq / 128) * Eq, 256, 0, stream>>>(
        X, W1T, H, nullptr, nullptr, nullptr, Mq, DFFq, Dq);

    transpose_cvt<<<dim3(Dq / 64, DFFq / 64, Eq), 256, 0, stream>>>(W2, W2T, DFFq, Dq);
    // GEMM2: out[token] = gate * (H @ W2): 20 x 8 x 8 = 1280 blocks
    gemm_nt<1><<<(Mq / 128) * (Dq / 128) * Eq, 256, 0, stream>>>(
        H, W2T, nullptr, out, tfs, gate, Mq, Dq, DFFq);
}

// Round 14
// 502.933 us; speedup vs baseline: 1.5823x; 1.0742x over previous
//
#include <hip/hip_runtime.h>

// MoE switch layer: B=8, N=2048, D=1024, E=8, DFF=4096, CAP=320
#define Bq 8
#define Nq 2048
#define Dq 1024
#define Eq 8
#define DFFq 4096
#define CAPq 320
#define Mq (Bq * CAPq)   // 2560 rows per expert
#define Tq (Bq * Nq)     // 16384 tokens

typedef __attribute__((ext_vector_type(8))) short bf16x8;
typedef __attribute__((ext_vector_type(4))) float f32x4;

static __device__ __forceinline__ unsigned short f2bf(float f) {
    union { float f; unsigned u; } v;
    v.f = f;
    unsigned r = v.u + 0x7fffu + ((v.u >> 16) & 1u);   // RNE
    return (unsigned short)(r >> 16);
}

static __device__ __forceinline__ void gload_lds16(const void* g, void* l) {
    __builtin_amdgcn_global_load_lds(
        (const __attribute__((address_space(1))) unsigned int*)g,
        (__attribute__((address_space(3))) unsigned int*)l, 16, 0, 0);
}

// ---------------- routing: logits -> softmax -> argmax/gate ----------------
__global__ __launch_bounds__(256) void route_kernel(
    const float* __restrict__ tok, const float* __restrict__ Wg,
    int* __restrict__ eidx, float* __restrict__ gate)
{
    int wv = threadIdx.x >> 6, lane = threadIdx.x & 63;
    int t = blockIdx.x * 4 + wv;
    const float* tp = tok + (size_t)t * Dq;
    float acc[8] = {0.f,0.f,0.f,0.f,0.f,0.f,0.f,0.f};
    for (int it = 0; it < Dq / 64; ++it) {
        int d = it * 64 + lane;
        float x = tp[d];
        const float4* w = (const float4*)(Wg + (size_t)d * 8);
        float4 w0 = w[0], w1 = w[1];
        acc[0] += x * w0.x; acc[1] += x * w0.y; acc[2] += x * w0.z; acc[3] += x * w0.w;
        acc[4] += x * w1.x; acc[5] += x * w1.y; acc[6] += x * w1.z; acc[7] += x * w1.w;
    }
#pragma unroll
    for (int e = 0; e < 8; ++e)
#pragma unroll
        for (int off = 32; off; off >>= 1)
            acc[e] += __shfl_xor(acc[e], off, 64);
    if (lane == 0) {
        float m = acc[0]; int bi = 0;
#pragma unroll
        for (int e = 1; e < 8; ++e) if (acc[e] > m) { m = acc[e]; bi = e; }
        float s = 0.f;
#pragma unroll
        for (int e = 0; e < 8; ++e) s += expf(acc[e] - m);
        eidx[t] = bi;
        gate[t] = 1.0f / s;   // max prob
    }
}

// ------------- slot assignment + zero dropped-token output rows ------------
__global__ __launch_bounds__(64) void slot_kernel(
    const int* __restrict__ eidx, int* __restrict__ tfs,
    float* __restrict__ out)
{
    int b = blockIdx.x >> 3, e = blockIdx.x & 7;
    int lane = threadIdx.x;
    const int* ip = eidx + (size_t)b * Nq;
    int base = (e * Bq + b) * CAPq;
    int cnt = 0;
    for (int it = 0; it < Nq / 64; ++it) {
        int n = it * 64 + lane;
        bool my = (ip[n] == e);
        unsigned long long mask = __ballot(my);
        if (my) {
            int pos = cnt + __popcll(mask & ((1ull << lane) - 1ull));
            if (pos < CAPq) {
                tfs[base + pos] = b * Nq + n;
            } else {
                // dropped token: its output row must be zero
                float4 z = {0.f, 0.f, 0.f, 0.f};
                float4* op = (float4*)(out + (size_t)(b * Nq + n) * Dq);
                for (int q = 0; q < Dq / 4; ++q) op[q] = z;
            }
        }
        cnt += __popcll(mask);
    }
}

// ------------- dispatch: gather token rows -> bf16 expert buffers ----------
__global__ __launch_bounds__(128) void dispatch_kernel(
    const float* __restrict__ tok, const int* __restrict__ tfs,
    unsigned short* __restrict__ X)
{
    int r = blockIdx.x;          // 0 .. E*B*CAP-1
    int t = tfs[r];
    int d0 = threadIdx.x * 8;
    unsigned short o[8];
    if (t < 0) {
#pragma unroll
        for (int k = 0; k < 8; ++k) o[k] = 0;
    } else {
        const float4* p = (const float4*)(tok + (size_t)t * Dq + d0);
        float4 a = p[0], b = p[1];
        o[0]=f2bf(a.x); o[1]=f2bf(a.y); o[2]=f2bf(a.z); o[3]=f2bf(a.w);
        o[4]=f2bf(b.x); o[5]=f2bf(b.y); o[6]=f2bf(b.z); o[7]=f2bf(b.w);
    }
    *(uint4*)(X + (size_t)r * Dq + d0) = *(const uint4*)o;
}

// ------- weight transpose+convert: in [E][R][C] f32 -> out [E][C][R] bf16 --
// 64x64 tile, float4 loads, LDS [64][65] (2-way banks max on both phases),
// uint4 (8x bf16) coalesced writes (128B per 8-lane cluster).
__global__ __launch_bounds__(256) void transpose_cvt(
    const float* __restrict__ in, unsigned short* __restrict__ out,
    int R, int C)
{
    __shared__ float tile[64][65];
    int e = blockIdx.z;
    int c0 = blockIdx.x * 64, r0 = blockIdx.y * 64;
    const float* ip = in + (size_t)e * R * C;
    int lr  = threadIdx.x >> 4;
    int lc4 = (threadIdx.x & 15) * 4;
#pragma unroll
    for (int i = 0; i < 4; ++i) {
        float4 v = *(const float4*)(ip + (size_t)(r0 + lr + 16 * i) * C + c0 + lc4);
        tile[lr + 16 * i][lc4 + 0] = v.x;
        tile[lr + 16 * i][lc4 + 1] = v.y;
        tile[lr + 16 * i][lc4 + 2] = v.z;
        tile[lr + 16 * i][lc4 + 3] = v.w;
    }
    __syncthreads();
    unsigned short* op = out + (size_t)e * R * C;   // out is [C][R]
    int oc  = threadIdx.x >> 3;    // 0..31 (column within tile, +32 on pass 2)
    int oct = threadIdx.x & 7;     // r-octet 0..7
#pragma unroll
    for (int i = 0; i < 2; ++i) {
        int c = oc + 32 * i;
        unsigned short o[8];
#pragma unroll
        for (int j = 0; j < 8; ++j)
            o[j] = f2bf(tile[oct * 8 + j][c]);
        *(uint4*)(op + (size_t)(c0 + c) * R + r0 + oct * 8) = *(const uint4*)o;
    }
}

// ====== r1-verified 128x128 NT GEMM, XCD swizzle + L2 supertile remap ======
// C[M][N] = A[M][K] * Bt[N][K]^T per expert. 256 thr = 4 waves (2M x 2N),
// per-wave 64x64, BK=64 single buffer, 2-barrier loop, 4 blocks/CU
// (launch_bounds(256,4); r13: occupancy 41%, MfmaUtil 35%).
// NEW: within-expert supertile remap (10 mb x 8 nb = 80 blocks): the ~128
// concurrently-resident blocks per XCD then touch ~2.5MB A + ~2-4MB B
// (mostly L2-resident) instead of 4 A-panels + 32 B-panels (9MB, thrash).
// r13 measured FETCH 594MB (GEMM1); ideal w/ remap ~180-350MB.
// Requires M == 2560 (MT=20 divisible by 10) and NTB % 8 == 0 -- true for
// both call sites. MODE 0: H = relu(C) bf16. MODE 1: gated scatter to Out.
template <int MODE>
__global__ __launch_bounds__(256, 4) void gemm_nt(
    const unsigned short* __restrict__ A,   // [E][M][K] bf16
    const unsigned short* __restrict__ Bt,  // [E][N][K] bf16
    unsigned short* __restrict__ Hout,      // [E][M][N] bf16  (MODE 0)
    float* __restrict__ Out,                // [T][D] f32      (MODE 1)
    const int* __restrict__ tfs,            // [E][M]
    const float* __restrict__ gate,         // [T]
    int M, int N, int K)
{
    __shared__ __align__(16) unsigned short As[128 * 64];
    __shared__ __align__(16) unsigned short Bs[128 * 64];
    __shared__ int   t_lds[128];
    __shared__ float g_lds[128];

    const int tid = threadIdx.x;

    // XCD-aware bijective swizzle (grid % 8 == 0): one expert per XCD here
    const int NTB = N >> 7, MT = M >> 7;
    const int nwg = MT * NTB * Eq;
    int flat = blockIdx.x;
    int wg = (flat & 7) * (nwg >> 3) + (flat >> 3);
    const int per_e = MT * NTB;
    int e   = wg / per_e;
    int rem = wg - e * per_e;

    // L2 supertile remap: 10 mb x 8 nb per supertile; scol fastest in band.
    int sup = rem / 80, inner = rem - sup * 80;
    const int nScol = NTB >> 3;                  // 4 (GEMM1) / 1 (GEMM2)
    int band = sup / nScol, scol = sup - band * nScol;
    int im = inner >> 3, inn = inner & 7;
    const int mb = band * 10 + im, nb = scol * 8 + inn;
    const int m0 = mb << 7, n0 = nb << 7;

    const unsigned short* Ae = A  + (size_t)e * M * K + (size_t)m0 * K;
    const unsigned short* Be = Bt + (size_t)e * N * K + (size_t)n0 * K;

    if (MODE == 1 && tid < 128) {
        int t = tfs[e * M + m0 + tid];
        t_lds[tid] = t;
        g_lds[tid] = (t >= 0) ? gate[t] : 0.f;
    }

    const int lane = tid & 63;
    const int wv = tid >> 6;
    const int wr = wv >> 1, wc = wv & 1;
    const int lrow = lane & 15;
    const int lk = lane >> 4;
    const int swz = (lrow & 7) << 4;

    // staging decode (constant per thread): LDS off = inst*4096 + tid*16
    const int srow = tid >> 3;                                     // row within 32-row chunk
    const int skb  = ((tid & 7) << 4) ^ (((tid >> 3) & 7) << 4);   // pre-swizzled src byte
    const int ldst = (tid >> 6) << 10;                             // wave-uniform dest

    f32x4 acc[4][4] = {};

    for (int kt = 0; kt < K; kt += 64) {
        __syncthreads();
        const char* ga = (const char*)Ae + ((size_t)srow * K + kt) * 2 + skb;
        const char* gb = (const char*)Be + ((size_t)srow * K + kt) * 2 + skb;
#pragma unroll
        for (int inst = 0; inst < 4; ++inst) {
            gload_lds16(ga + (size_t)(inst * 32) * K * 2, (char*)As + inst * 4096 + ldst);
            gload_lds16(gb + (size_t)(inst * 32) * K * 2, (char*)Bs + inst * 4096 + ldst);
        }
        __syncthreads();
#pragma unroll
        for (int kk = 0; kk < 2; ++kk) {
            bf16x8 af[4], bfr[4];
#pragma unroll
            for (int i = 0; i < 4; ++i) {
                int row = wr * 64 + i * 16 + lrow;
                int addr = row * 128 + ((kk * 64 + lk * 16) ^ swz);
                af[i] = *(const bf16x8*)((const char*)As + addr);
            }
#pragma unroll
            for (int j = 0; j < 4; ++j) {
                int row = wc * 64 + j * 16 + lrow;
                int addr = row * 128 + ((kk * 64 + lk * 16) ^ swz);
                bfr[j] = *(const bf16x8*)((const char*)Bs + addr);
            }
            __builtin_amdgcn_s_setprio(1);
#pragma unroll
            for (int i = 0; i < 4; ++i)
#pragma unroll
                for (int j = 0; j < 4; ++j)
                    acc[i][j] = __builtin_amdgcn_mfma_f32_16x16x32_bf16(
                        af[i], bfr[j], acc[i][j], 0, 0, 0);
            __builtin_amdgcn_s_setprio(0);
        }
    }

    if (MODE == 0) {
        unsigned short* Hp = Hout + (size_t)e * M * N;
#pragma unroll
        for (int i = 0; i < 4; ++i) {
            int row = m0 + wr * 64 + i * 16 + lk * 4;
#pragma unroll
            for (int j = 0; j < 4; ++j) {
                int col = n0 + wc * 64 + j * 16 + lrow;
#pragma unroll
                for (int r = 0; r < 4; ++r)
                    Hp[(size_t)(row + r) * N + col] = f2bf(fmaxf(acc[i][j][r], 0.f));
            }
        }
    } else {
#pragma unroll
        for (int i = 0; i < 4; ++i) {
            int rowl = wr * 64 + i * 16 + lk * 4;
#pragma unroll
            for (int r = 0; r < 4; ++r) {
                int t = t_lds[rowl + r];
                if (t < 0) continue;
                float g = g_lds[rowl + r];
#pragma unroll
                for (int j = 0; j < 4; ++j) {
                    int col = n0 + wc * 64 + j * 16 + lrow;
                    Out[(size_t)t * Dq + col] = g * acc[i][j][r];
                }
            }
        }
    }
}

// ---------------------------------------------------------------------------
extern "C" void kernel_launch(void* const* d_in, const int* in_sizes, int n_in,
                              void* d_out, int out_size, void* d_ws, size_t ws_size,
                              hipStream_t stream)
{
    const float* tok = (const float*)d_in[0];
    const float* Wg  = (const float*)d_in[1];
    const float* W1  = (const float*)d_in[2];
    const float* W2  = (const float*)d_in[3];
    float* out = (float*)d_out;
    char* ws = (char*)d_ws;

    // workspace layout (bytes)
    unsigned short* W1T = (unsigned short*)(ws);                    // [E][DFF][D] bf16  67108864
    unsigned short* W2T = (unsigned short*)(ws + 67108864);         // [E][D][DFF] bf16  67108864
    unsigned short* X   = (unsigned short*)(ws + 134217728);        // [E][M][D]  bf16   41943040
    unsigned short* H   = (unsigned short*)(ws + 176160768);        // [E][M][DFF] bf16 167772160
    int*   tfs  = (int*)(ws + 343932928);                           // [E][M]            81920
    int*   eidx = (int*)(ws + 344014848);                           // [T]               65536
    float* gate = (float*)(ws + 344080384);                         // [T]               65536

    hipMemsetAsync(tfs, 0xFF, Eq * Mq * 4, stream);

    route_kernel<<<Tq / 4, 256, 0, stream>>>(tok, Wg, eidx, gate);
    slot_kernel<<<Bq * Eq, 64, 0, stream>>>(eidx, tfs, out);
    dispatch_kernel<<<Eq * Mq, 128, 0, stream>>>(tok, tfs, X);

    // W1 transpose immediately before GEMM1 (L2 warmth), W2 before GEMM2
    transpose_cvt<<<dim3(DFFq / 64, Dq / 64, Eq), 256, 0, stream>>>(W1, W1T, Dq, DFFq);
    // GEMM1: H = relu(X @ W1): 20 x 32 x 8 = 5120 blocks
    gemm_nt<0><<<(Mq / 128) * (DFFq / 128) * Eq, 256, 0, stream>>>(
        X, W1T, H, nullptr, nullptr, nullptr, Mq, DFFq, Dq);

    transpose_cvt<<<dim3(Dq / 64, DFFq / 64, Eq), 256, 0, stream>>>(W2, W2T, DFFq, Dq);
    // GEMM2: out[token] = gate * (H @ W2): 20 x 8 x 8 = 1280 blocks
    gemm_nt<1><<<(Mq / 128) * (Dq / 128) * Eq, 256, 0, stream>>>(
        H, W2T, nullptr, out, tfs, gate, Mq, Dq, DFFq);
}